// Round 1
// baseline (461.931 us; speedup 1.0000x reference)
//
#include <hip/hip_runtime.h>
#include <hip/hip_cooperative_groups.h>
#include <math.h>

namespace cg = cooperative_groups;

#define SEQ 65536
#define H2  1024

typedef float f4 __attribute__((ext_vector_type(4)));

// ---------------------------------------------------------------------------
// A1: partial[oc][h] = sum_{o in chunk oc (16 rows)} wv[o] * W[o,h]
// grid (4, 64), block 256. Coalesced over h; 16 KB of W per block.
// ---------------------------------------------------------------------------
__global__ void reduce_W_partial(const float* __restrict__ W,
                                 const float* __restrict__ wv,
                                 float* __restrict__ partial) {
    const int h  = blockIdx.x * 256 + threadIdx.x;
    const int oc = blockIdx.y;
    const int o0 = oc * 16;
    float acc = 0.0f;
#pragma unroll
    for (int j = 0; j < 16; ++j)
        acc += wv[o0 + j] * W[(size_t)(o0 + j) * H2 + h];
    partial[oc * H2 + h] = acc;
}

// ---------------------------------------------------------------------------
// A2: v[h] = sum_oc partial[oc][h].  grid 4, block 256. Deterministic fold.
// ---------------------------------------------------------------------------
__global__ void fold_v(const float* __restrict__ partial,
                       float* __restrict__ v) {
    const int h = blockIdx.x * 256 + threadIdx.x;
    float acc = 0.0f;
#pragma unroll 8
    for (int oc = 0; oc < 64; ++oc) acc += partial[oc * H2 + h];
    v[h] = acc;
}

// ---------------------------------------------------------------------------
// B+C fused (cooperative): e[s] = dot(outputs[s,:], v) kept in registers;
// per-block (m,s) published; grid.sync(); every block redundantly merges the
// 1024 (m,s) pairs (8 KB, L2-hot, fixed order -> bit-identical across blocks)
// and normalizes its own 64 rows straight from registers.
// grid 1024 x 256 = exactly 4 blocks/CU; launch_bounds(256,4) guarantees
// cooperative co-residency (VGPR <= 128).
// Saves: softmax dispatch + 1 launch + the e[] 512 KB round-trip.
// ---------------------------------------------------------------------------
__global__ void __launch_bounds__(256, 4) row_softmax(
        const f4* __restrict__ outputs,   // [SEQ, 256] as float4
        const f4* __restrict__ v4,        // [256] float4
        float* __restrict__ bmax,         // [1024]
        float* __restrict__ bsum,         // [1024]
        float* __restrict__ out) {        // [SEQ]
    const int b    = blockIdx.x;
    const int t    = threadIdx.x;
    const int w    = t >> 6;
    const int lane = t & 63;

    const f4 vr0 = v4[lane];
    const f4 vr1 = v4[lane + 64];
    const f4 vr2 = v4[lane + 128];
    const f4 vr3 = v4[lane + 192];

    const int r0 = b * 64 + w * 16;
    float m = -INFINITY, s = 0.0f, myval = 0.0f;

#pragma unroll 4
    for (int j = 0; j < 16; ++j) {
        const f4* rp = outputs + (size_t)(r0 + j) * 256;
        // single-use 268 MB stream: non-temporal, don't pollute L2/L3
        const f4 a0 = __builtin_nontemporal_load(rp + lane);
        const f4 a1 = __builtin_nontemporal_load(rp + lane + 64);
        const f4 a2 = __builtin_nontemporal_load(rp + lane + 128);
        const f4 a3 = __builtin_nontemporal_load(rp + lane + 192);
        float acc = a0.x * vr0.x + a0.y * vr0.y + a0.z * vr0.z + a0.w * vr0.w;
        acc      += a1.x * vr1.x + a1.y * vr1.y + a1.z * vr1.z + a1.w * vr1.w;
        acc      += a2.x * vr2.x + a2.y * vr2.y + a2.z * vr2.z + a2.w * vr2.w;
        acc      += a3.x * vr3.x + a3.y * vr3.y + a3.z * vr3.z + a3.w * vr3.w;
        // butterfly all-reduce: every lane ends with the full row sum
#pragma unroll
        for (int off = 1; off < 64; off <<= 1)
            acc += __shfl_xor(acc, off, 64);
        if (lane == j) myval = acc;
        // online (m, s) update -- wave-uniform
        const float d = acc - m;
        if (d > 0.0f) { s = s * __expf(-d) + 1.0f; m = acc; }
        else          { s += __expf(d); }
    }

    __shared__ float lm[4], ls[4];
    __shared__ float rm[256], rs[256];
    if (lane == 0) { lm[w] = m; ls[w] = s; }
    __syncthreads();
    if (t == 0) {
        float M = lm[0], S = ls[0];
#pragma unroll
        for (int i = 1; i < 4; ++i) {
            const float Mn = fmaxf(M, lm[i]);
            S = S * __expf(M - Mn) + ls[i] * __expf(lm[i] - Mn);
            M = Mn;
        }
        bmax[b] = M;
        bsum[b] = S;
    }

    // ---- all blocks' stats published; device-scope fence + barrier ----
    cg::this_grid().sync();

    // ---- redundant global merge (identical order in every block) ----
    float M = -INFINITY, S = 0.0f;
#pragma unroll
    for (int i = 0; i < 4; ++i) {
        const int idx = t + 256 * i;               // coalesced
        const float m2 = bmax[idx], s2 = bsum[idx];
        const float Mn = fmaxf(M, m2);
        S = S * __expf(M - Mn) + s2 * __expf(m2 - Mn);
        M = Mn;
    }
    rm[t] = M; rs[t] = S;
    __syncthreads();
    for (int stride = 128; stride > 0; stride >>= 1) {
        if (t < stride) {
            const float M1 = rm[t], S1 = rs[t];
            const float M2 = rm[t + stride], S2 = rs[t + stride];
            const float Mn = fmaxf(M1, M2);
            rm[t] = Mn;
            rs[t] = S1 * __expf(M1 - Mn) + S2 * __expf(M2 - Mn);
        }
        __syncthreads();
    }
    const float Mg  = rm[0];
    const float inv = 1.0f / rs[0];

    // ---- normalize straight from registers (lane j holds row j's dot) ----
    if (lane < 16) out[r0 + lane] = __expf(myval - Mg) * inv;
}

// ---------------------------------------------------------------------------
extern "C" void kernel_launch(void* const* d_in, const int* in_sizes, int n_in,
                              void* d_out, int out_size, void* d_ws, size_t ws_size,
                              hipStream_t stream) {
    const float* outputs = (const float*)d_in[0];  // [SEQ, H2]
    const float* W       = (const float*)d_in[1];  // [H2, H2]
    // d_in[2] = b  -- unused: softmax is shift-invariant
    const float* wv      = (const float*)d_in[3];  // [1, H2]
    float* out = (float*)d_out;

    float* ws = (float*)d_ws;
    float* v       = ws;                       // 1024
    float* partial = ws + H2;                  // 64*1024
    float* bmax    = partial + 64 * H2;        // 1024
    float* bsum    = bmax + 1024;              // 1024

    reduce_W_partial<<<dim3(4, 64), 256, 0, stream>>>(W, wv, partial);
    fold_v<<<4, 256, 0, stream>>>(partial, v);

    const f4* o4  = (const f4*)outputs;
    const f4* v4p = (const f4*)v;
    void* args[] = {(void*)&o4, (void*)&v4p, (void*)&bmax, (void*)&bsum, (void*)&out};
    hipLaunchCooperativeKernel((const void*)row_softmax, dim3(1024), dim3(256),
                               args, 0, stream);
}

// Round 2
// 374.778 us; speedup vs baseline: 1.2325x; 1.2325x over previous
//
#include <hip/hip_runtime.h>
#include <math.h>

#define SEQ 65536
#define H2  1024

// ---------------------------------------------------------------------------
// A1: partial[oc][h] = sum_{o in chunk oc (16 rows)} wv[o] * W[o,h]
// grid (4, 64), block 256. Coalesced over h; 16 KB of W per block.
// ---------------------------------------------------------------------------
__global__ void reduce_W_partial(const float* __restrict__ W,
                                 const float* __restrict__ wv,
                                 float* __restrict__ partial) {
    const int h  = blockIdx.x * 256 + threadIdx.x;
    const int oc = blockIdx.y;
    const int o0 = oc * 16;
    float acc = 0.0f;
#pragma unroll
    for (int j = 0; j < 16; ++j)
        acc += wv[o0 + j] * W[(size_t)(o0 + j) * H2 + h];
    partial[oc * H2 + h] = acc;
}

// ---------------------------------------------------------------------------
// A2: v[h] = sum_oc partial[oc][h].  grid 32 x 256: 8 threads per column,
// each sums 8 chunks (coalesced 32-wide), LDS tree-combine. Deterministic.
// Was 4 blocks (4 CUs, ~2.7 us BW/CU-bound); 32 blocks -> ~1 us latency floor.
// ---------------------------------------------------------------------------
__global__ void fold_v(const float* __restrict__ partial,
                       float* __restrict__ v) {
    const int t   = threadIdx.x;
    const int c   = t & 31;          // column within block's 32-column strip
    const int sub = t >> 5;          // 0..7: which 8-chunk slice to sum
    const int h   = blockIdx.x * 32 + c;
    float acc = 0.0f;
#pragma unroll
    for (int j = 0; j < 8; ++j)
        acc += partial[(sub * 8 + j) * H2 + h];
    __shared__ float sh[8][32];
    sh[sub][c] = acc;
    __syncthreads();
    if (t < 32) {
        float s = sh[0][t];
#pragma unroll
        for (int j = 1; j < 8; ++j) s += sh[j][t];
        v[blockIdx.x * 32 + t] = s;
    }
}

// ---------------------------------------------------------------------------
// B: e[s] = dot(outputs[s,:], v) + flash-style per-block (m, s) partials.
// grid 1024 blocks x 256 thr; wave handles 16 rows; 1 KB/row coalesced.
// This is the BW carrier: 256 MB streaming read.
// ---------------------------------------------------------------------------
__global__ void __launch_bounds__(256) row_dot(
        const float4* __restrict__ outputs,   // [SEQ, 256] as float4
        const float4* __restrict__ v4,        // [256] float4
        float* __restrict__ e,                // [SEQ]
        float* __restrict__ bmax,             // [1024]
        float* __restrict__ bsum) {           // [1024]
    const int b    = blockIdx.x;
    const int t    = threadIdx.x;
    const int w    = t >> 6;
    const int lane = t & 63;

    const float4 vr0 = v4[lane];
    const float4 vr1 = v4[lane + 64];
    const float4 vr2 = v4[lane + 128];
    const float4 vr3 = v4[lane + 192];

    const int r0 = b * 64 + w * 16;
    float m = -INFINITY, s = 0.0f, myval = 0.0f;

#pragma unroll 4
    for (int j = 0; j < 16; ++j) {
        const float4* rp = outputs + (size_t)(r0 + j) * 256;
        const float4 a0 = rp[lane];
        const float4 a1 = rp[lane + 64];
        const float4 a2 = rp[lane + 128];
        const float4 a3 = rp[lane + 192];
        float acc = a0.x * vr0.x + a0.y * vr0.y + a0.z * vr0.z + a0.w * vr0.w;
        acc      += a1.x * vr1.x + a1.y * vr1.y + a1.z * vr1.z + a1.w * vr1.w;
        acc      += a2.x * vr2.x + a2.y * vr2.y + a2.z * vr2.z + a2.w * vr2.w;
        acc      += a3.x * vr3.x + a3.y * vr3.y + a3.z * vr3.z + a3.w * vr3.w;
        // butterfly all-reduce: every lane ends with the full row sum
#pragma unroll
        for (int off = 1; off < 64; off <<= 1)
            acc += __shfl_xor(acc, off, 64);
        if (lane == j) myval = acc;
        // online (m, s) update -- wave-uniform
        const float d = acc - m;
        if (d > 0.0f) { s = s * __expf(-d) + 1.0f; m = acc; }
        else          { s += __expf(d); }
    }
    if (lane < 16) e[r0 + lane] = myval;

    __shared__ float lm[4], ls[4];
    if (lane == 0) { lm[w] = m; ls[w] = s; }
    __syncthreads();
    if (t == 0) {
        float M = lm[0], S = ls[0];
#pragma unroll
        for (int i = 1; i < 4; ++i) {
            const float Mn = fmaxf(M, lm[i]);
            S = S * __expf(M - Mn) + ls[i] * __expf(lm[i] - Mn);
            M = Mn;
        }
        bmax[b] = M;
        bsum[b] = S;
    }
}

// ---------------------------------------------------------------------------
// C (fused): every block redundantly merges the 1024 (m,s) pairs (8 KB,
// L2-hot), then normalizes its 256 rows. grid 256, block 256.
// ---------------------------------------------------------------------------
__global__ void __launch_bounds__(256) softmax_norm_fused(
        const float* __restrict__ e,
        const float* __restrict__ bmax,
        const float* __restrict__ bsum,
        float* __restrict__ out) {
    const int t = threadIdx.x;
    float M = -INFINITY, S = 0.0f;
#pragma unroll
    for (int i = 0; i < 4; ++i) {
        const int idx = t + 256 * i;               // coalesced
        const float m2 = bmax[idx], s2 = bsum[idx];
        const float Mn = fmaxf(M, m2);
        S = S * __expf(M - Mn) + s2 * __expf(m2 - Mn);
        M = Mn;
    }
    __shared__ float rm[256], rs[256];
    rm[t] = M; rs[t] = S;
    __syncthreads();
    for (int stride = 128; stride > 0; stride >>= 1) {
        if (t < stride) {
            const float M1 = rm[t], S1 = rs[t];
            const float M2 = rm[t + stride], S2 = rs[t + stride];
            const float Mn = fmaxf(M1, M2);
            rm[t] = Mn;
            rs[t] = S1 * __expf(M1 - Mn) + S2 * __expf(M2 - Mn);
        }
        __syncthreads();
    }
    const float Mg  = rm[0];
    const float inv = 1.0f / rs[0];

    const int i = blockIdx.x * 256 + t;
    out[i] = __expf(e[i] - Mg) * inv;
}

// ---------------------------------------------------------------------------
extern "C" void kernel_launch(void* const* d_in, const int* in_sizes, int n_in,
                              void* d_out, int out_size, void* d_ws, size_t ws_size,
                              hipStream_t stream) {
    const float* outputs = (const float*)d_in[0];  // [SEQ, H2]
    const float* W       = (const float*)d_in[1];  // [H2, H2]
    // d_in[2] = b  -- unused: softmax is shift-invariant
    const float* wv      = (const float*)d_in[3];  // [1, H2]
    float* out = (float*)d_out;

    float* ws = (float*)d_ws;
    float* v       = ws;                       // 1024
    float* partial = ws + H2;                  // 64*1024
    float* e       = partial + 64 * H2;        // SEQ
    float* bmax    = e + SEQ;                  // 1024
    float* bsum    = bmax + 1024;              // 1024

    reduce_W_partial<<<dim3(4, 64), 256, 0, stream>>>(W, wv, partial);
    fold_v<<<32, 256, 0, stream>>>(partial, v);
    row_dot<<<1024, 256, 0, stream>>>((const float4*)outputs,
                                      (const float4*)v, e, bmax, bsum);
    softmax_norm_fused<<<SEQ / 256, 256, 0, stream>>>(e, bmax, bsum, out);
}

// Round 3
// 347.849 us; speedup vs baseline: 1.3280x; 1.0774x over previous
//
#include <hip/hip_runtime.h>
#include <math.h>

#define SEQ 65536
#define H2  1024

typedef float f4 __attribute__((ext_vector_type(4)));

// ---------------------------------------------------------------------------
// A1: partial[oc][h] = sum_{o in chunk oc (16 rows)} wv[o] * W[o,h]
// grid (4, 64), block 256. Coalesced over h; 16 KB of W per block.
// ---------------------------------------------------------------------------
__global__ void reduce_W_partial(const float* __restrict__ W,
                                 const float* __restrict__ wv,
                                 float* __restrict__ partial) {
    const int h  = blockIdx.x * 256 + threadIdx.x;
    const int oc = blockIdx.y;
    const int o0 = oc * 16;
    float acc = 0.0f;
#pragma unroll
    for (int j = 0; j < 16; ++j)
        acc += wv[o0 + j] * W[(size_t)(o0 + j) * H2 + h];
    partial[oc * H2 + h] = acc;
}

// ---------------------------------------------------------------------------
// A2: v[h] = sum_oc partial[oc][h].  grid 32 x 256: 8 threads per column,
// each sums 8 chunks (coalesced 32-wide), LDS tree-combine. Deterministic.
// ---------------------------------------------------------------------------
__global__ void fold_v(const float* __restrict__ partial,
                       float* __restrict__ v) {
    const int t   = threadIdx.x;
    const int c   = t & 31;          // column within block's 32-column strip
    const int sub = t >> 5;          // 0..7: which 8-chunk slice to sum
    const int h   = blockIdx.x * 32 + c;
    float acc = 0.0f;
#pragma unroll
    for (int j = 0; j < 8; ++j)
        acc += partial[(sub * 8 + j) * H2 + h];
    __shared__ float sh[8][32];
    sh[sub][c] = acc;
    __syncthreads();
    if (t < 32) {
        float s = sh[0][t];
#pragma unroll
        for (int j = 1; j < 8; ++j) s += sh[j][t];
        v[blockIdx.x * 32 + t] = s;
    }
}

// ---------------------------------------------------------------------------
// B: e[s] = dot(outputs[s,:], v) + flash-style per-block (m, s) partials.
// grid 1024 blocks x 256 thr; wave handles 16 rows; 1 KB/row coalesced.
// BW carrier: 268 MB streaming read > 256 MB L3 -> zero reuse -> NT loads
// (ISOLATED change this round: skip L2/L3 allocation churn on the stream).
// ---------------------------------------------------------------------------
__global__ void __launch_bounds__(256) row_dot(
        const f4* __restrict__ outputs,   // [SEQ, 256] as float4
        const f4* __restrict__ v4,        // [256] float4
        float* __restrict__ e,            // [SEQ]
        float* __restrict__ bmax,         // [1024]
        float* __restrict__ bsum) {       // [1024]
    const int b    = blockIdx.x;
    const int t    = threadIdx.x;
    const int w    = t >> 6;
    const int lane = t & 63;

    const f4 vr0 = v4[lane];
    const f4 vr1 = v4[lane + 64];
    const f4 vr2 = v4[lane + 128];
    const f4 vr3 = v4[lane + 192];

    const int r0 = b * 64 + w * 16;
    float m = -INFINITY, s = 0.0f, myval = 0.0f;

#pragma unroll 4
    for (int j = 0; j < 16; ++j) {
        const f4* rp = outputs + (size_t)(r0 + j) * 256;
        const f4 a0 = __builtin_nontemporal_load(rp + lane);
        const f4 a1 = __builtin_nontemporal_load(rp + lane + 64);
        const f4 a2 = __builtin_nontemporal_load(rp + lane + 128);
        const f4 a3 = __builtin_nontemporal_load(rp + lane + 192);
        float acc = a0.x * vr0.x + a0.y * vr0.y + a0.z * vr0.z + a0.w * vr0.w;
        acc      += a1.x * vr1.x + a1.y * vr1.y + a1.z * vr1.z + a1.w * vr1.w;
        acc      += a2.x * vr2.x + a2.y * vr2.y + a2.z * vr2.z + a2.w * vr2.w;
        acc      += a3.x * vr3.x + a3.y * vr3.y + a3.z * vr3.z + a3.w * vr3.w;
        // butterfly all-reduce: every lane ends with the full row sum
#pragma unroll
        for (int off = 1; off < 64; off <<= 1)
            acc += __shfl_xor(acc, off, 64);
        if (lane == j) myval = acc;
        // online (m, s) update -- wave-uniform
        const float d = acc - m;
        if (d > 0.0f) { s = s * __expf(-d) + 1.0f; m = acc; }
        else          { s += __expf(d); }
    }
    if (lane < 16) e[r0 + lane] = myval;

    __shared__ float lm[4], ls[4];
    if (lane == 0) { lm[w] = m; ls[w] = s; }
    __syncthreads();
    if (t == 0) {
        float M = lm[0], S = ls[0];
#pragma unroll
        for (int i = 1; i < 4; ++i) {
            const float Mn = fmaxf(M, lm[i]);
            S = S * __expf(M - Mn) + ls[i] * __expf(lm[i] - Mn);
            M = Mn;
        }
        bmax[b] = M;
        bsum[b] = S;
    }
}

// ---------------------------------------------------------------------------
// C (fused): every block redundantly merges the 1024 (m,s) pairs (8 KB,
// L2-hot), then normalizes its 256 rows. grid 256, block 256.
// ---------------------------------------------------------------------------
__global__ void __launch_bounds__(256) softmax_norm_fused(
        const float* __restrict__ e,
        const float* __restrict__ bmax,
        const float* __restrict__ bsum,
        float* __restrict__ out) {
    const int t = threadIdx.x;
    float M = -INFINITY, S = 0.0f;
#pragma unroll
    for (int i = 0; i < 4; ++i) {
        const int idx = t + 256 * i;               // coalesced
        const float m2 = bmax[idx], s2 = bsum[idx];
        const float Mn = fmaxf(M, m2);
        S = S * __expf(M - Mn) + s2 * __expf(m2 - Mn);
        M = Mn;
    }
    __shared__ float rm[256], rs[256];
    rm[t] = M; rs[t] = S;
    __syncthreads();
    for (int stride = 128; stride > 0; stride >>= 1) {
        if (t < stride) {
            const float M1 = rm[t], S1 = rs[t];
            const float M2 = rm[t + stride], S2 = rs[t + stride];
            const float Mn = fmaxf(M1, M2);
            rm[t] = Mn;
            rs[t] = S1 * __expf(M1 - Mn) + S2 * __expf(M2 - Mn);
        }
        __syncthreads();
    }
    const float Mg  = rm[0];
    const float inv = 1.0f / rs[0];

    const int i = blockIdx.x * 256 + t;
    out[i] = __expf(e[i] - Mg) * inv;
}

// ---------------------------------------------------------------------------
extern "C" void kernel_launch(void* const* d_in, const int* in_sizes, int n_in,
                              void* d_out, int out_size, void* d_ws, size_t ws_size,
                              hipStream_t stream) {
    const float* outputs = (const float*)d_in[0];  // [SEQ, H2]
    const float* W       = (const float*)d_in[1];  // [H2, H2]
    // d_in[2] = b  -- unused: softmax is shift-invariant
    const float* wv      = (const float*)d_in[3];  // [1, H2]
    float* out = (float*)d_out;

    float* ws = (float*)d_ws;
    float* v       = ws;                       // 1024
    float* partial = ws + H2;                  // 64*1024
    float* e       = partial + 64 * H2;        // SEQ
    float* bmax    = e + SEQ;                  // 1024
    float* bsum    = bmax + 1024;              // 1024

    reduce_W_partial<<<dim3(4, 64), 256, 0, stream>>>(W, wv, partial);
    fold_v<<<32, 256, 0, stream>>>(partial, v);
    row_dot<<<1024, 256, 0, stream>>>((const f4*)outputs,
                                      (const f4*)v, e, bmax, bsum);
    softmax_norm_fused<<<SEQ / 256, 256, 0, stream>>>(e, bmax, bsum, out);
}